// Round 15
// baseline (374.952 us; speedup 1.0000x reference)
//
#include <hip/hip_runtime.h>
#include <hip/hip_bf16.h>
#include <stdint.h>

// ---------- types ----------
typedef __attribute__((ext_vector_type(8)))  short bf16x8;
typedef __attribute__((ext_vector_type(4)))  float f32x4;
typedef __attribute__((ext_vector_type(4)))  float float4v;
typedef __attribute__((ext_vector_type(8)))  unsigned short u16x8;

#define MFMA16(a,b,c) __builtin_amdgcn_mfma_f32_16x16x32_bf16((a),(b),(c),0,0,0)

__device__ __forceinline__ unsigned short f2bf(float f) {
    unsigned int u = __builtin_bit_cast(unsigned int, f);
    u = (u + 0x7fffu + ((u >> 16) & 1u)) >> 16;
    return (unsigned short)u;
}

__device__ __forceinline__ void gload_lds16(const void* g, void* l) {
    __builtin_amdgcn_global_load_lds(
        (const __attribute__((address_space(1))) void*)g,
        (__attribute__((address_space(3))) void*)l, 16, 0, 0);
}

template<int N> __device__ __forceinline__ void waitvm() {}  // N<0: no wait
template<> __device__ __forceinline__ void waitvm<0>() { asm volatile("s_waitcnt vmcnt(0)" ::: "memory"); }

// ---------- fp32 -> bf16 convert: hs and vt in ONE launch (BW floor ~69 us) ----------
__global__ void cvt_all(const float* __restrict__ hs, const float* __restrict__ vt,
                        unsigned short* __restrict__ hs_bf, unsigned short* __restrict__ vt_bf) {
    if (blockIdx.x < 2048) {
        long i = ((long)blockIdx.x * blockDim.x + threadIdx.x) * 8;
        const long stride = 2048L * 256 * 8;
        for (; i < 67108864L; i += stride) {
            float4v v0 = *(const float4v*)(hs + i);
            float4v v1 = *(const float4v*)(hs + i + 4);
            u16x8 o;
            o[0] = f2bf(v0[0]); o[1] = f2bf(v0[1]); o[2] = f2bf(v0[2]); o[3] = f2bf(v0[3]);
            o[4] = f2bf(v1[0]); o[5] = f2bf(v1[1]); o[6] = f2bf(v1[2]); o[7] = f2bf(v1[3]);
            *(u16x8*)(hs_bf + i) = o;
        }
    } else {
        long i = ((long)(blockIdx.x - 2048) * blockDim.x + threadIdx.x) * 8;
        const long stride = 512L * 256 * 8;
        for (; i < 8388608L; i += stride) {
            float4v v0 = *(const float4v*)(vt + i);
            float4v v1 = *(const float4v*)(vt + i + 4);
            u16x8 o;
            o[0] = f2bf(v0[0]); o[1] = f2bf(v0[1]); o[2] = f2bf(v0[2]); o[3] = f2bf(v0[3]);
            o[4] = f2bf(v1[0]); o[5] = f2bf(v1[1]); o[6] = f2bf(v1[2]); o[7] = f2bf(v1[3]);
            *(u16x8*)(vt_bf + i) = o;
        }
    }
}

// ---------- GEMM1: z = H(bf16) @ VT(bf16)^T, 256x256 tile, 16x16x32 MFMA ----------
// FOUR-PHASE single-barrier schedule (round-12's model, phases merged 8->4).
// Safety rule (re-derived): a wave staging in phase p has passed BAR(p-1) =>
// all waves executed lgkm(0) in BAR(p-2) => all tail-reads from phases <= p-3
// are drained. All restage gaps below are EXACTLY 3.
//
// Iter j computes tile u=2j (bufs0: PA,PB) and v=2j+1 (bufs1: PC,PD);
// stages tile 2j+1 -> bufs1 (PA: A1.h0,B1.h0,B1.h1 [6]; PB: A1.h1 [2])
// and tile 2j+2 -> bufs0 (PC: A0.h0,B0.h0,B0.h1 [6]; PD: A0.h1 [2]).
// Tails (after 32-MFMA cluster, before end-of-phase wait):
//   PA: aO<-bA0.h1 [staged PD(j-1), retired W(PD,j-1), vis BAR(PA)]
//   PB: aE,b0,b1<-bufs1 [staged PA(j), retired W(PA), vis BAR(PB)]
//   PC: aO<-bA1.h1 [staged PB(j), retired W(PB), vis BAR(PC)]
//   PD: aE,b0,b1<-bufs0 [staged PC(j), retired W(PC), vis BAR(PD)]
// Waits: vmcnt(0) at end of every phase; each covers only DMAs issued at the
// START of the same phase (~1 full phase of MFMA in between > HBM latency).
// Restage-gap audit (read-phase -> stage-phase, all = 3):
//   bufs1 {A1.h0,B1.h0,B1.h1}: tail(PB,j-1) -> PA(j).  A1.h1: tail(PC,j-1) -> PB(j).
//   bufs0 {A0.h0,B0.h0,B0.h1}: tail(PD,j-1) -> PC(j).  A0.h1: tail(PA,j) -> PD(j).
// j=0 edges: bufs1 never read before PA(0); bufs0 prologue-tail reads (phase
// "-1") are 3 phases before PC(0)=phase 2. Final iter j=31: SU=false, TD=false.

#define STAGE_A(nA_, k0n, h, l) \
    gload_lds16(pA + ((l)*128 + (h)*64) * 4096L + (k0n), (nA_) + dA0 + ((l)*128 + (h)*64) * 64)
#define STAGE_B(nB_, k0n, h, l) \
    gload_lds16(pB + ((l)*128 + (h)*32) * 4096L + (k0n), (nB_) + dB0 + ((l)*128 + (h)*32) * 64)

#define LDA(dst_, sA_, QM) do { _Pragma("unroll") for (int mi = 0; mi < 4; ++mi) { \
    dst_[mi][0] = *(const bf16x8*)((sA_) + ((wr*128 + (QM)*64 + mi*16 + lan15) << 6) + g0); \
    dst_[mi][1] = *(const bf16x8*)((sA_) + ((wr*128 + (QM)*64 + mi*16 + lan15) << 6) + (g0 ^ 32)); } } while (0)
#define LDB(dst_, sB_, QN) do { _Pragma("unroll") for (int ni = 0; ni < 2; ++ni) { \
    dst_[ni][0] = *(const bf16x8*)((sB_) + ((wc*64 + (QN)*32 + ni*16 + lan15) << 6) + g0); \
    dst_[ni][1] = *(const bf16x8*)((sB_) + ((wc*64 + (QN)*32 + ni*16 + lan15) << 6) + (g0 ^ 32)); } } while (0)

#define DOMFMA(QM, QN, aset_, bset_) do { \
    _Pragma("unroll") for (int mi = 0; mi < 4; ++mi) \
      _Pragma("unroll") for (int ni = 0; ni < 2; ++ni) { \
        acc[(QM)*4+mi][(QN)*2+ni] = MFMA16(aset_[mi][0], bset_[ni][0], acc[(QM)*4+mi][(QN)*2+ni]); \
        acc[(QM)*4+mi][(QN)*2+ni] = MFMA16(aset_[mi][1], bset_[ni][1], acc[(QM)*4+mi][(QN)*2+ni]); } \
    } while (0)

#define BARX() do { __builtin_amdgcn_s_barrier(); \
    asm volatile("s_waitcnt lgkmcnt(0)" ::: "memory"); \
    __builtin_amdgcn_sched_barrier(0); } while (0)
#define SB() __builtin_amdgcn_sched_barrier(0)

#define ITER4(KV, KU2, SV, SU, TD, WC_, WD_) do { \
  /*PA*/ if (SV) { STAGE_A(bA1, KV, 0, 0); STAGE_A(bA1, KV, 0, 1); \
                   STAGE_B(bB1, KV, 0, 0); STAGE_B(bB1, KV, 0, 1); \
                   STAGE_B(bB1, KV, 1, 0); STAGE_B(bB1, KV, 1, 1); } \
         BARX(); __builtin_amdgcn_s_setprio(1); \
         DOMFMA(0, 0, aE, b0); DOMFMA(0, 1, aE, b1); \
         __builtin_amdgcn_s_setprio(0); \
         LDA(aO, bA0, 1); waitvm<0>(); SB(); \
  /*PB*/ if (SV) { STAGE_A(bA1, KV, 1, 0); STAGE_A(bA1, KV, 1, 1); } \
         BARX(); __builtin_amdgcn_s_setprio(1); \
         DOMFMA(1, 1, aO, b1); DOMFMA(1, 0, aO, b0); \
         __builtin_amdgcn_s_setprio(0); \
         LDA(aE, bA1, 0); LDB(b0, bB1, 0); LDB(b1, bB1, 1); waitvm<0>(); SB(); \
  /*PC*/ if (SU) { STAGE_A(bA0, KU2, 0, 0); STAGE_A(bA0, KU2, 0, 1); \
                   STAGE_B(bB0, KU2, 0, 0); STAGE_B(bB0, KU2, 0, 1); \
                   STAGE_B(bB0, KU2, 1, 0); STAGE_B(bB0, KU2, 1, 1); } \
         BARX(); __builtin_amdgcn_s_setprio(1); \
         DOMFMA(0, 0, aE, b0); DOMFMA(0, 1, aE, b1); \
         __builtin_amdgcn_s_setprio(0); \
         LDA(aO, bA1, 1); waitvm<WC_>(); SB(); \
  /*PD*/ if (SU) { STAGE_A(bA0, KU2, 1, 0); STAGE_A(bA0, KU2, 1, 1); } \
         BARX(); __builtin_amdgcn_s_setprio(1); \
         DOMFMA(1, 1, aO, b1); DOMFMA(1, 0, aO, b0); \
         __builtin_amdgcn_s_setprio(0); \
         if (TD) { LDA(aE, bA0, 0); LDB(b0, bB0, 0); LDB(b1, bB0, 1); } \
         waitvm<WD_>(); SB(); \
} while (0)

__global__ __launch_bounds__(512, 2) void gemm1_4ph(const unsigned short* __restrict__ A,  // [16384][4096]
                                                    const unsigned short* __restrict__ B,  // [2048][4096]
                                                    unsigned short* __restrict__ Z) {      // [16384][2048]
    __shared__ __align__(16) unsigned short lds[65536];   // 128 KiB

    const int tid   = threadIdx.x;
    const int lane  = tid & 63;
    const int wid   = tid >> 6;
    const int wr    = wid >> 2;          // 0..1
    const int wc    = wid & 3;           // 0..3
    const int lan15 = lane & 15;
    const int g0    = (((lane >> 4) ^ (lane & 7)) << 3);

    const int  bid = blockIdx.x;
    const long m0  = (long)(bid >> 3) * 256;
    const long n0  = (long)(bid & 7) * 256;

    const int q8    = tid >> 3;
    const int granA = (((tid & 7) ^ (q8 & 7)) << 3);
    const unsigned short* pA = A + (m0 + q8) * 4096L + granA;
    const int rB0   = (q8 & 31) + ((q8 >> 5) << 6);
    const unsigned short* pB = B + (n0 + rB0) * 4096L + granA;
    const int dA0   = (wid * 8) * 64;
    const int dB0   = ((wid & 3) * 8 + ((wid >> 2) << 6)) * 64;

    f32x4 acc[8][4] = {};
    bf16x8 aE[4][2], aO[4][2], b0[2][2], b1[2][2];

    unsigned short* bA0 = lds;
    unsigned short* bB0 = lds + 16384;
    unsigned short* bA1 = lds + 32768;
    unsigned short* bB1 = lds + 49152;

    // ---- prologue: stage tile 0 only (bufs1 is staged inside PA/PB(0)) ----
    STAGE_A(bA0, 0, 0, 0);  STAGE_A(bA0, 0, 0, 1);
    STAGE_B(bB0, 0, 0, 0);  STAGE_B(bB0, 0, 0, 1);
    STAGE_B(bB0, 0, 1, 0);  STAGE_B(bB0, 0, 1, 1);
    STAGE_A(bA0, 0, 1, 0);  STAGE_A(bA0, 0, 1, 1);
    waitvm<0>();                        // retire tile 0 in every wave
    __builtin_amdgcn_s_barrier();       // visibility for all waves
    __builtin_amdgcn_sched_barrier(0);
    LDA(aE, bA0, 0); LDB(b0, bB0, 0); LDB(b1, bB0, 1);  // prologue tail
    SB();

    // ---- main loop: j = 0..30 (computes tiles 0..61; stages 1..62) ----
    for (int j = 0; j < 31; ++j) {
        ITER4((2 * j + 1) * 64, (2 * j + 2) * 64, true, true, true, 0, 0);
    }
    // ---- final iter j=31 (tiles 62,63): stage only tile 63 (PA/PB) ----
    ITER4(63 * 64, 0, true, false, false, 0, -1);

    // ---- epilogue: z bf16 store; C/D col = lane&15 (n), row = (lane>>4)*4+j ----
    const int rq = (lane >> 4) << 2;
    #pragma unroll
    for (int mi = 0; mi < 8; ++mi) {
        #pragma unroll
        for (int ni = 0; ni < 4; ++ni) {
            const long mb  = m0 + wr * 128 + mi * 16 + rq;
            const long nb2 = n0 + wc * 64 + ni * 16 + lan15;
            #pragma unroll
            for (int j = 0; j < 4; ++j)
                Z[(mb + j) * 2048L + nb2] = f2bf(acc[mi][ni][j]);
        }
    }
}

// ---------- GEMM2: grouped up-projection (write-BW floor ~54 us) ----------
#define U_PAD 80

__global__ __launch_bounds__(256) void gemm2(const unsigned short* __restrict__ Z,  // [16384][2048] bf16
                                             const float* __restrict__ U,           // [32][128][64] f32
                                             float* __restrict__ out) {             // [16384][4096] f32
    __shared__ __align__(16) unsigned short lU[128 * U_PAD];

    const int tid  = threadIdx.x;
    const int lane = tid & 63;
    const int wid  = tid >> 6;
    const int g    = blockIdx.x & 31;
    const long m0  = (long)(blockIdx.x >> 5) * 64;

    const float* ug = U + (long)g * (128 * 64);
    for (int i = tid; i < (128 * 64) / 4; i += 256) {
        const int r = i >> 4;
        const int c = (i << 2) & 63;
        float4v v = *(const float4v*)(ug + i * 4);
        unsigned short* d = &lU[r * U_PAD + c];
        d[0] = f2bf(v[0]); d[1] = f2bf(v[1]); d[2] = f2bf(v[2]); d[3] = f2bf(v[3]);
    }
    __syncthreads();

    const long mrow = m0 + wid * 16 + (lane & 15);
    const unsigned short* zrow = Z + mrow * 2048L + g * 64 + ((lane >> 4) << 3);
    const bf16x8 a0 = *(const bf16x8*)(zrow);
    const bf16x8 a1 = *(const bf16x8*)(zrow + 32);

    f32x4 acc[8] = {};
    const int blds = (lane & 15);
    const int kofs = (lane >> 4) << 3;
    #pragma unroll
    for (int ni = 0; ni < 8; ++ni) {
        const bf16x8 c0 = *(const bf16x8*)&lU[(ni * 16 + blds) * U_PAD + kofs];
        const bf16x8 c1 = *(const bf16x8*)&lU[(ni * 16 + blds) * U_PAD + 32 + kofs];
        acc[ni] = MFMA16(a0, c0, acc[ni]);
        acc[ni] = MFMA16(a1, c1, acc[ni]);
    }

    const long mb = m0 + wid * 16 + ((lane >> 4) << 2);
    const long cb = (long)g * 128 + (lane & 15);
    #pragma unroll
    for (int ni = 0; ni < 8; ++ni)
        #pragma unroll
        for (int j = 0; j < 4; ++j)
            out[(mb + j) * 4096L + cb + ni * 16] = acc[ni][j];
}

// ---------- launch ----------
extern "C" void kernel_launch(void* const* d_in, const int* in_sizes, int n_in,
                              void* d_out, int out_size, void* d_ws, size_t ws_size,
                              hipStream_t stream) {
    const float* hs = (const float*)d_in[0];   // [4,4096,4096] fp32
    const float* vt = (const float*)d_in[1];   // [2048,4096]   fp32
    const float* uw = (const float*)d_in[2];   // [32,128,64]   fp32
    float* out = (float*)d_out;

    unsigned short* hs_bf = (unsigned short*)d_ws;            // 67108864 bf16
    unsigned short* vt_bf = hs_bf + 67108864L;                //  8388608 bf16
    unsigned short* z_bf  = vt_bf + 8388608L;                 // 33554432 bf16

    // one conversion launch: blocks 0..2047 -> hs, 2048..2559 -> vt
    cvt_all<<<2560, 256, 0, stream>>>(hs, vt, hs_bf, vt_bf);

    // GEMM1: (16384/256) x (2048/256) = 64 x 8 = 512 blocks, 512 threads
    gemm1_4ph<<<512, 512, 0, stream>>>(hs_bf, vt_bf, z_bf);

    // GEMM2: (16384/64) x 32 groups = 8192 blocks
    gemm2<<<8192, 256, 0, stream>>>(z_bf, uw, out);
}

// Round 16
// 360.709 us; speedup vs baseline: 1.0395x; 1.0395x over previous
//
#include <hip/hip_runtime.h>
#include <hip/hip_bf16.h>
#include <stdint.h>

// ---------- types ----------
typedef __attribute__((ext_vector_type(8)))  short bf16x8;
typedef __attribute__((ext_vector_type(4)))  float f32x4;
typedef __attribute__((ext_vector_type(4)))  float float4v;
typedef __attribute__((ext_vector_type(8)))  unsigned short u16x8;

#define MFMA16(a,b,c) __builtin_amdgcn_mfma_f32_16x16x32_bf16((a),(b),(c),0,0,0)

__device__ __forceinline__ unsigned short f2bf(float f) {
    unsigned int u = __builtin_bit_cast(unsigned int, f);
    u = (u + 0x7fffu + ((u >> 16) & 1u)) >> 16;
    return (unsigned short)u;
}

__device__ __forceinline__ void gload_lds16(const void* g, void* l) {
    __builtin_amdgcn_global_load_lds(
        (const __attribute__((address_space(1))) void*)g,
        (__attribute__((address_space(3))) void*)l, 16, 0, 0);
}

template<int N> __device__ __forceinline__ void waitvm() {}  // N<0: no wait
template<> __device__ __forceinline__ void waitvm<6>() { asm volatile("s_waitcnt vmcnt(6)" ::: "memory"); }
template<> __device__ __forceinline__ void waitvm<4>() { asm volatile("s_waitcnt vmcnt(4)" ::: "memory"); }
template<> __device__ __forceinline__ void waitvm<0>() { asm volatile("s_waitcnt vmcnt(0)" ::: "memory"); }

// ---------- fp32 -> bf16 convert: hs and vt in ONE launch (BW floor ~69 us) ----------
__global__ void cvt_all(const float* __restrict__ hs, const float* __restrict__ vt,
                        unsigned short* __restrict__ hs_bf, unsigned short* __restrict__ vt_bf) {
    if (blockIdx.x < 2048) {
        long i = ((long)blockIdx.x * blockDim.x + threadIdx.x) * 8;
        const long stride = 2048L * 256 * 8;
        for (; i < 67108864L; i += stride) {
            float4v v0 = *(const float4v*)(hs + i);
            float4v v1 = *(const float4v*)(hs + i + 4);
            u16x8 o;
            o[0] = f2bf(v0[0]); o[1] = f2bf(v0[1]); o[2] = f2bf(v0[2]); o[3] = f2bf(v0[3]);
            o[4] = f2bf(v1[0]); o[5] = f2bf(v1[1]); o[6] = f2bf(v1[2]); o[7] = f2bf(v1[3]);
            *(u16x8*)(hs_bf + i) = o;
        }
    } else {
        long i = ((long)(blockIdx.x - 2048) * blockDim.x + threadIdx.x) * 8;
        const long stride = 512L * 256 * 8;
        for (; i < 8388608L; i += stride) {
            float4v v0 = *(const float4v*)(vt + i);
            float4v v1 = *(const float4v*)(vt + i + 4);
            u16x8 o;
            o[0] = f2bf(v0[0]); o[1] = f2bf(v0[1]); o[2] = f2bf(v0[2]); o[3] = f2bf(v0[3]);
            o[4] = f2bf(v1[0]); o[5] = f2bf(v1[1]); o[6] = f2bf(v1[2]); o[7] = f2bf(v1[3]);
            *(u16x8*)(vt_bf + i) = o;
        }
    }
}

// ---------- GEMM1: z = H(bf16) @ VT(bf16)^T, 256x256 tile, 16x16x32 MFMA ----------
// Round-12 verified SINGLE-BARRIER 8-phase schedule (221 us, MfmaUtil 56%,
// 0 bank conflicts, absmax 0.25). Safety model: a wave issuing stage(p) has
// passed BAR(p-1) => all waves arrived BAR(p-1) => all executed lgkm(0) after
// BAR(p-2) => all drained tail-reads from phases <= p-3. All restage gaps = 3.
//
// Stage map (iter i computes u=2i, v=2i+1; stages u+2 -> bufs0, v+2 -> bufs1):
//   P1: Ah1(v)->A1.h1 [2]     P3: Ah0(u+2)->A0.h0, Bh0(u+2)->B0.h0 [4]
//   P4: Bh1(u+2)->B0.h1 [2]   P5: Ah1(u+2)->A0.h1 [2]
//   P7: Ah0(v+2)->A1.h0, Bh0(v+2)->B1.h0 [4]   P8: Bh1(v+2)->B1.h1 [2]
// Waits: W3 = vmcnt(4) end-P3 (retires thru P1(i)); W7 = vmcnt(4) end-P7
// (retires thru P5(i)). All ds_reads are TAILS (after DOMFMA):
//   P1: b1<-B0.h1   P2: aO<-A0.h1   P4: aE<-A1.h0, b0<-B1.h0
//   P5: b1<-B1.h1   P6: aO<-A1.h1   P8: aE<-A0.h0, b0<-B0.h0
// Every tail sits after its covering wait's barrier (cross-wave visibility);
// every stage->wait spans >= 2 phases (HBM latency).

#define STAGE_A(nA_, k0n, h, l) \
    gload_lds16(pA + ((l)*128 + (h)*64) * 4096L + (k0n), (nA_) + dA0 + ((l)*128 + (h)*64) * 64)
#define STAGE_B(nB_, k0n, h, l) \
    gload_lds16(pB + ((l)*128 + (h)*32) * 4096L + (k0n), (nB_) + dB0 + ((l)*128 + (h)*32) * 64)

#define LDA(dst_, sA_, QM) do { _Pragma("unroll") for (int mi = 0; mi < 4; ++mi) { \
    dst_[mi][0] = *(const bf16x8*)((sA_) + ((wr*128 + (QM)*64 + mi*16 + lan15) << 6) + g0); \
    dst_[mi][1] = *(const bf16x8*)((sA_) + ((wr*128 + (QM)*64 + mi*16 + lan15) << 6) + (g0 ^ 32)); } } while (0)
#define LDB(dst_, sB_, QN) do { _Pragma("unroll") for (int ni = 0; ni < 2; ++ni) { \
    dst_[ni][0] = *(const bf16x8*)((sB_) + ((wc*64 + (QN)*32 + ni*16 + lan15) << 6) + g0); \
    dst_[ni][1] = *(const bf16x8*)((sB_) + ((wc*64 + (QN)*32 + ni*16 + lan15) << 6) + (g0 ^ 32)); } } while (0)

#define DOMFMA(QM, QN, aset_, bset_) do { __builtin_amdgcn_s_setprio(1); \
    _Pragma("unroll") for (int mi = 0; mi < 4; ++mi) \
      _Pragma("unroll") for (int ni = 0; ni < 2; ++ni) { \
        acc[(QM)*4+mi][(QN)*2+ni] = MFMA16(aset_[mi][0], bset_[ni][0], acc[(QM)*4+mi][(QN)*2+ni]); \
        acc[(QM)*4+mi][(QN)*2+ni] = MFMA16(aset_[mi][1], bset_[ni][1], acc[(QM)*4+mi][(QN)*2+ni]); } \
    __builtin_amdgcn_s_setprio(0); } while (0)

#define BARX() do { __builtin_amdgcn_s_barrier(); \
    asm volatile("s_waitcnt lgkmcnt(0)" ::: "memory"); \
    __builtin_amdgcn_sched_barrier(0); } while (0)
#define SB() __builtin_amdgcn_sched_barrier(0)

#define ITER8(K1, K2, K3, S2, S3, T8, V3, V7) do { \
  /*P1*/ STAGE_A(bA1, K1, 1, 0); STAGE_A(bA1, K1, 1, 1); \
         BARX(); DOMFMA(0, 0, aE, b0); LDB(b1, bB0, 1); SB(); \
  /*P2*/ BARX(); DOMFMA(0, 1, aE, b1); LDA(aO, bA0, 1); SB(); \
  /*P3*/ if (S2) { STAGE_A(bA0, K2, 0, 0); STAGE_A(bA0, K2, 0, 1); \
                   STAGE_B(bB0, K2, 0, 0); STAGE_B(bB0, K2, 0, 1); } \
         BARX(); DOMFMA(1, 1, aO, b1); waitvm<V3>(); SB(); \
  /*P4*/ if (S2) { STAGE_B(bB0, K2, 1, 0); STAGE_B(bB0, K2, 1, 1); } \
         BARX(); DOMFMA(1, 0, aO, b0); LDA(aE, bA1, 0); LDB(b0, bB1, 0); SB(); \
  /*P5*/ if (S2) { STAGE_A(bA0, K2, 1, 0); STAGE_A(bA0, K2, 1, 1); } \
         BARX(); DOMFMA(0, 0, aE, b0); LDB(b1, bB1, 1); SB(); \
  /*P6*/ BARX(); DOMFMA(0, 1, aE, b1); LDA(aO, bA1, 1); SB(); \
  /*P7*/ if (S3) { STAGE_A(bA1, K3, 0, 0); STAGE_A(bA1, K3, 0, 1); \
                   STAGE_B(bB1, K3, 0, 0); STAGE_B(bB1, K3, 0, 1); } \
         BARX(); DOMFMA(1, 1, aO, b1); waitvm<V7>(); SB(); \
  /*P8*/ if (S3) { STAGE_B(bB1, K3, 1, 0); STAGE_B(bB1, K3, 1, 1); } \
         BARX(); DOMFMA(1, 0, aO, b0); \
         if (T8) { LDA(aE, bA0, 0); LDB(b0, bB0, 0); } SB(); \
} while (0)

__global__ __launch_bounds__(512, 2) void gemm1_8ph(const unsigned short* __restrict__ A,  // [16384][4096]
                                                    const unsigned short* __restrict__ B,  // [2048][4096]
                                                    unsigned short* __restrict__ Z) {      // [16384][2048]
    __shared__ __align__(16) unsigned short lds[65536];   // 128 KiB

    const int tid   = threadIdx.x;
    const int lane  = tid & 63;
    const int wid   = tid >> 6;
    const int wr    = wid >> 2;          // 0..1
    const int wc    = wid & 3;           // 0..3
    const int lan15 = lane & 15;
    const int g0    = (((lane >> 4) ^ (lane & 7)) << 3);

    const int  bid = blockIdx.x;
    const long m0  = (long)(bid >> 3) * 256;
    const long n0  = (long)(bid & 7) * 256;

    const int q8    = tid >> 3;
    const int granA = (((tid & 7) ^ (q8 & 7)) << 3);
    const unsigned short* pA = A + (m0 + q8) * 4096L + granA;
    const int rB0   = (q8 & 31) + ((q8 >> 5) << 6);
    const unsigned short* pB = B + (n0 + rB0) * 4096L + granA;
    const int dA0   = (wid * 8) * 64;
    const int dB0   = ((wid & 3) * 8 + ((wid >> 2) << 6)) * 64;

    f32x4 acc[8][4] = {};
    bf16x8 aE[4][2], aO[4][2], b0[2][2], b1[2][2];

    unsigned short* bA0 = lds;
    unsigned short* bB0 = lds + 16384;
    unsigned short* bA1 = lds + 32768;
    unsigned short* bB1 = lds + 49152;

    // ---- prologue ----
    STAGE_A(bA0, 0, 0, 0);  STAGE_A(bA0, 0, 0, 1);
    STAGE_B(bB0, 0, 0, 0);  STAGE_B(bB0, 0, 0, 1);
    STAGE_B(bB0, 0, 1, 0);  STAGE_B(bB0, 0, 1, 1);
    STAGE_A(bA0, 0, 1, 0);  STAGE_A(bA0, 0, 1, 1);
    STAGE_A(bA1, 64, 0, 0); STAGE_A(bA1, 64, 0, 1);
    STAGE_B(bB1, 64, 0, 0); STAGE_B(bB1, 64, 0, 1);
    STAGE_B(bB1, 64, 1, 0); STAGE_B(bB1, 64, 1, 1);
    waitvm<6>();            // retires t0's 8 issues in every wave
    __builtin_amdgcn_s_barrier();       // visibility for all waves
    __builtin_amdgcn_sched_barrier(0);
    LDA(aE, bA0, 0); LDB(b0, bB0, 0);   // prologue tail (drains at P1's BARX)
    SB();

    // ---- main loop: iters 0..30 (tiles 0..61 computed, 2..63 staged) ----
    for (int i = 0; i < 31; ++i) {
        ITER8((2 * i + 1) * 64, (2 * i + 2) * 64, (2 * i + 3) * 64,
              true, true, true, 4, 4);
    }
    // ---- final iter (tiles 62,63): stage only P1's Ah1(63); V3 drains ----
    ITER8(63 * 64, 0, 0, false, false, false, 0, -1);

    // ---- epilogue: z bf16 store; C/D col = lane&15 (n), row = (lane>>4)*4+j ----
    const int rq = (lane >> 4) << 2;
    #pragma unroll
    for (int mi = 0; mi < 8; ++mi) {
        #pragma unroll
        for (int ni = 0; ni < 4; ++ni) {
            const long mb  = m0 + wr * 128 + mi * 16 + rq;
            const long nb2 = n0 + wc * 64 + ni * 16 + lan15;
            #pragma unroll
            for (int j = 0; j < 4; ++j)
                Z[(mb + j) * 2048L + nb2] = f2bf(acc[mi][ni][j]);
        }
    }
}

// ---------- GEMM2: grouped up-projection (write-BW floor ~54 us) ----------
#define U_PAD 80

__global__ __launch_bounds__(256) void gemm2(const unsigned short* __restrict__ Z,  // [16384][2048] bf16
                                             const float* __restrict__ U,           // [32][128][64] f32
                                             float* __restrict__ out) {             // [16384][4096] f32
    __shared__ __align__(16) unsigned short lU[128 * U_PAD];

    const int tid  = threadIdx.x;
    const int lane = tid & 63;
    const int wid  = tid >> 6;
    const int g    = blockIdx.x & 31;
    const long m0  = (long)(blockIdx.x >> 5) * 64;

    const float* ug = U + (long)g * (128 * 64);
    for (int i = tid; i < (128 * 64) / 4; i += 256) {
        const int r = i >> 4;
        const int c = (i << 2) & 63;
        float4v v = *(const float4v*)(ug + i * 4);
        unsigned short* d = &lU[r * U_PAD + c];
        d[0] = f2bf(v[0]); d[1] = f2bf(v[1]); d[2] = f2bf(v[2]); d[3] = f2bf(v[3]);
    }
    __syncthreads();

    const long mrow = m0 + wid * 16 + (lane & 15);
    const unsigned short* zrow = Z + mrow * 2048L + g * 64 + ((lane >> 4) << 3);
    const bf16x8 a0 = *(const bf16x8*)(zrow);
    const bf16x8 a1 = *(const bf16x8*)(zrow + 32);

    f32x4 acc[8] = {};
    const int blds = (lane & 15);
    const int kofs = (lane >> 4) << 3;
    #pragma unroll
    for (int ni = 0; ni < 8; ++ni) {
        const bf16x8 c0 = *(const bf16x8*)&lU[(ni * 16 + blds) * U_PAD + kofs];
        const bf16x8 c1 = *(const bf16x8*)&lU[(ni * 16 + blds) * U_PAD + 32 + kofs];
        acc[ni] = MFMA16(a0, c0, acc[ni]);
        acc[ni] = MFMA16(a1, c1, acc[ni]);
    }

    const long mb = m0 + wid * 16 + ((lane >> 4) << 2);
    const long cb = (long)g * 128 + (lane & 15);
    #pragma unroll
    for (int ni = 0; ni < 8; ++ni)
        #pragma unroll
        for (int j = 0; j < 4; ++j)
            out[(mb + j) * 4096L + cb + ni * 16] = acc[ni][j];
}

// ---------- launch ----------
extern "C" void kernel_launch(void* const* d_in, const int* in_sizes, int n_in,
                              void* d_out, int out_size, void* d_ws, size_t ws_size,
                              hipStream_t stream) {
    const float* hs = (const float*)d_in[0];   // [4,4096,4096] fp32
    const float* vt = (const float*)d_in[1];   // [2048,4096]   fp32
    const float* uw = (const float*)d_in[2];   // [32,128,64]   fp32
    float* out = (float*)d_out;

    unsigned short* hs_bf = (unsigned short*)d_ws;            // 67108864 bf16
    unsigned short* vt_bf = hs_bf + 67108864L;                //  8388608 bf16
    unsigned short* z_bf  = vt_bf + 8388608L;                 // 33554432 bf16

    // one conversion launch: blocks 0..2047 -> hs, 2048..2559 -> vt
    cvt_all<<<2560, 256, 0, stream>>>(hs, vt, hs_bf, vt_bf);

    // GEMM1: (16384/256) x (2048/256) = 64 x 8 = 512 blocks, 512 threads
    gemm1_8ph<<<512, 512, 0, stream>>>(hs_bf, vt_bf, z_bf);

    // GEMM2: (16384/64) x 32 groups = 8192 blocks
    gemm2<<<8192, 256, 0, stream>>>(z_bf, uw, out);
}